// Round 9
// baseline (82.445 us; speedup 1.0000x reference)
//
#include <hip/hip_runtime.h>
#include <cfloat>

// Shapes (fixed by reference)
#define Bb 4
#define Tt 12
#define Nn 307
#define Cc 64
#define TH 6000
#define Wn 200        // windows: starts = 0,30,...,5970
#define ROW (Nn*Cc)   // 19648 floats per time-row
#define NT (Tt*Nn)    // 3684
#define KTOP 10
#define NUMEL 943104.0f  // B*64*N*T

// sims decomposition
#define NCG_T 20      // 16-n chunk-groups per t (19 full + 1 of 3 n)
#define NCG (Tt*NCG_T)  // 240
#define NWG 8         // window-groups
#define WPG 25        // windows per group

// workspace layout (float offsets)
#define WS_MT   0                      // 4096  : Mt[c'*64+c]
#define WS_BC   4096                   // 64    : Bc[c]
#define WS_QWL  4160                   // 235776: QWl[t][n][c]
#define WS_PART (WS_QWL + Tt*ROW)      // 48000 : part[cgid][w]
#define WS_CORR (WS_PART + NCG*Wn)     // 10    : softmax weights
#define WS_IDX  (WS_CORR + KTOP)       // 10    : window indices (int)

// ---------- Kernel A: Mt = Wk^T Wq (transposed), Bc ----------
__global__ void prep_kernel(const float* __restrict__ Wq, const float* __restrict__ bq,
                            const float* __restrict__ Wk, float* __restrict__ ws) {
    __shared__ float wq[4096], wk[4096];
    for (int i = threadIdx.x; i < 4096; i += 256) { wq[i] = Wq[i]; wk[i] = Wk[i]; }
    __syncthreads();
    float* Mt = ws + WS_MT;
    for (int e = threadIdx.x; e < 4096; e += 256) {
        int cp = e >> 6, c = e & 63;
        float s = 0.f;
        #pragma unroll 8
        for (int o = 0; o < 64; ++o) s += wk[o*64 + c] * wq[o*64 + cp];
        Mt[e] = s;
    }
    if (threadIdx.x < 64) {
        int c = threadIdx.x;
        float s = 0.f;
        #pragma unroll 8
        for (int o = 0; o < 64; ++o) s += wk[o*64 + c] * bq[o];
        ws[WS_BC + c] = 4.0f * s;
    }
}

// ---------- Kernel B: QWl[t][n][c] = sum_c' Mt[c'][c]*Xs[t,n,c'] + Bc[c] ----------
__global__ void qw_kernel(const float* __restrict__ x, float* __restrict__ ws) {
    int blk = blockIdx.x;            // t*N + n
    int t = blk / Nn, n = blk % Nn;
    int c = threadIdx.x;             // 64 threads
    size_t base = ((size_t)t * Nn + n) * 64 + c;
    const size_t bs = (size_t)Tt * Nn * 64;
    float xs = x[base] + x[base + bs] + x[base + 2*bs] + x[base + 3*bs];
    __shared__ float xsl[64];
    xsl[c] = xs;
    __syncthreads();
    const float* Mt = ws + WS_MT;
    float q = ws[WS_BC + c];
    #pragma unroll 8
    for (int cp = 0; cp < 64; ++cp) q += Mt[cp*64 + c] * xsl[cp];
    ws[WS_QWL + (size_t)t * ROW + n*64 + c] = q;
}

// ---------- Kernel C: sims — register-resident a, 25-window streaming ----------
// Block = (chunk-group cgid = t*20+cg, window-group wg). Wave holds its 1KB
// a-fragment in registers; loops 25 windows: 1 coalesced 1KB hist load + 4 FMA
// each, into 25 independent accumulators. Reductions in epilogue only.
__global__ __launch_bounds__(256) void sims_kernel(const float* __restrict__ hist,
                                                   const float* __restrict__ ws_ro,
                                                   float* __restrict__ part) {
    int blk  = blockIdx.x;           // 0..1919
    int wg   = blk % NWG;
    int cgid = blk / NWG;            // 0..239
    int t  = cgid / NCG_T;
    int cg = cgid % NCG_T;
    int wv   = threadIdx.x >> 6;     // wave 0..3
    int lane = threadIdx.x & 63;
    int n  = cg*16 + wv*4 + (lane >> 4);   // wave covers 4 consecutive n
    int c4 = (lane & 15) * 4;
    bool valid = (n < Nn);
    int ne = valid ? n : (Nn - 1);
    size_t rowoff = (size_t)ne * 64 + c4;

    float4 av = *(const float4*)(ws_ro + WS_QWL + (size_t)t * ROW + rowoff);
    if (!valid) av = make_float4(0.f, 0.f, 0.f, 0.f);

    const float* hbase = hist + (size_t)t * ROW + rowoff;
    int w0 = wg * WPG;
    float s[WPG];
    #pragma unroll
    for (int wi = 0; wi < WPG; ++wi) {
        float4 bv = *(const float4*)(hbase + (size_t)(30*(w0 + wi)) * ROW);
        s[wi] = av.x*bv.x + av.y*bv.y + av.z*bv.z + av.w*bv.w;
    }
    #pragma unroll
    for (int wi = 0; wi < WPG; ++wi) {
        float v = s[wi];
        #pragma unroll
        for (int off = 32; off > 0; off >>= 1) v += __shfl_down(v, off);
        s[wi] = v;                   // lane 0 holds wave total
    }
    __shared__ float red[4][WPG];
    if (lane == 0) {
        #pragma unroll
        for (int wi = 0; wi < WPG; ++wi) red[wv][wi] = s[wi];
    }
    __syncthreads();
    if (threadIdx.x < WPG)
        part[cgid*Wn + w0 + threadIdx.x] =
            red[0][threadIdx.x] + red[1][threadIdx.x] +
            red[2][threadIdx.x] + red[3][threadIdx.x];
}

// ---------- Kernel D: final — reduce part, top-10 (JAX tie-break), softmax ----------
__global__ void final_kernel(float* __restrict__ ws) {
    __shared__ float simsL[200];
    int tid = threadIdx.x;
    if (tid < 200) {
        const float* part = ws + WS_PART;
        float sum = 0.f;
        #pragma unroll 8
        for (int cg = 0; cg < NCG; ++cg) sum += part[cg*Wn + tid];
        simsL[tid] = sum / NUMEL;
    }
    __syncthreads();
    if (tid >= 64) return;
    int lane = tid;                  // one wave does selection
    float v[4]; int ji[4];
    #pragma unroll
    for (int r = 0; r < 4; ++r) {
        int j = lane + 64*r;         // sims index 0..198; value = sims_all[j+1]
        ji[r] = (j < Wn - 1) ? j : (1 << 29);
        v[r]  = (j < Wn - 1) ? simsL[j + 1] : -FLT_MAX;
    }
    float tv[KTOP]; int ti[KTOP];
    for (int k = 0; k < KTOP; ++k) {
        float bv = -FLT_MAX; int bi = 1 << 29;
        #pragma unroll
        for (int r = 0; r < 4; ++r)
            if (v[r] > bv || (v[r] == bv && ji[r] < bi)) { bv = v[r]; bi = ji[r]; }
        #pragma unroll
        for (int off = 32; off > 0; off >>= 1) {
            float ov = __shfl_xor(bv, off);
            int   oi = __shfl_xor(bi, off);
            if (ov > bv || (ov == bv && oi < bi)) { bv = ov; bi = oi; }
        }
        tv[k] = bv; ti[k] = bi;      // all lanes hold the result
        #pragma unroll
        for (int r = 0; r < 4; ++r) if (ji[r] == bi) v[r] = -FLT_MAX;
    }
    if (lane == 0) {
        float m = tv[0];
        float sum = 0.f, e[KTOP];
        for (int k = 0; k < KTOP; ++k) { e[k] = __expf(tv[k] - m); sum += e[k]; }
        float inv = 1.0f / sum;
        int* idxout = (int*)(ws + WS_IDX);
        for (int k = 0; k < KTOP; ++k) { ws[WS_CORR + k] = e[k] * inv; idxout[k] = ti[k]; }
    }
}

// ---------- Kernel E: aggregate + Wv/bv + broadcast (no top-k recompute) ----------
__global__ void agg_kernel(const float* __restrict__ hist, const float* __restrict__ Wv,
                           const float* __restrict__ bvv, const float* __restrict__ ws,
                           float* __restrict__ out) {
    int blk = blockIdx.x;            // t*N + n
    int t = blk / Nn, n = blk % Nn;
    int c = threadIdx.x;             // 64 threads; c doubles as output channel o
    const float* corr = ws + WS_CORR;
    const int* topi = (const int*)(ws + WS_IDX);
    float a = 0.f;
    #pragma unroll
    for (int k = 0; k < KTOP; ++k) {
        int w = topi[k];             // reference gathers windows[index] (un-shifted!)
        a += corr[k] * hist[(size_t)(30*w + t) * ROW + n*64 + c];
    }
    __shared__ float aw[64];
    aw[c] = a;
    __syncthreads();
    float acc = bvv[c];
    #pragma unroll 8
    for (int cc = 0; cc < 64; ++cc) acc += Wv[c*64 + cc] * aw[cc];
    #pragma unroll
    for (int b = 0; b < Bb; ++b)
        out[(((size_t)b*Tt + t)*Nn + n)*64 + c] = acc;
}

extern "C" void kernel_launch(void* const* d_in, const int* in_sizes, int n_in,
                              void* d_out, int out_size, void* d_ws, size_t ws_size,
                              hipStream_t stream) {
    const float* x    = (const float*)d_in[0];
    const float* hist = (const float*)d_in[1];
    const float* Wq   = (const float*)d_in[2];
    const float* bq   = (const float*)d_in[3];
    const float* Wk   = (const float*)d_in[4];
    // d_in[5] = bk: unused — uniform shift to all sims; top-k ordering and
    // softmax are shift-invariant, so the output is unaffected.
    const float* Wv   = (const float*)d_in[6];
    const float* bv   = (const float*)d_in[7];
    float* ws  = (float*)d_ws;
    float* out = (float*)d_out;

    prep_kernel<<<1, 256, 0, stream>>>(Wq, bq, Wk, ws);
    qw_kernel<<<NT, 64, 0, stream>>>(x, ws);
    sims_kernel<<<NCG*NWG, 256, 0, stream>>>(hist, ws, ws + WS_PART);
    final_kernel<<<1, 256, 0, stream>>>(ws);
    agg_kernel<<<NT, 64, 0, stream>>>(hist, Wv, bv, ws, out);
}

// Round 10
// 71.846 us; speedup vs baseline: 1.1475x; 1.1475x over previous
//
#include <hip/hip_runtime.h>
#include <cfloat>

// Shapes (fixed by reference)
#define Bb 4
#define Tt 12
#define Nn 307
#define Cc 64
#define TH 6000
#define Wn 200        // windows: starts = 0,30,...,5970
#define ROW (Nn*Cc)   // 19648 floats per time-row
#define NT (Tt*Nn)    // 3684
#define KTOP 10
#define NUMEL 943104.0f  // B*64*N*T

// sims decomposition: window x sixth-of-window (a sixth = exactly 2 rows = 157KB)
#define NS 6
#define SIXTH (2*ROW)    // 39296 floats
#define SIXTH4 (SIXTH/4) // 9824 float4s

// workspace layout (float offsets)
#define WS_MT   0                      // 4096  : Mt[c'*64+c]
#define WS_BC   4096                   // 64    : Bc[c]
#define WS_QWL  4160                   // 235776: QWl[t][n][c]  (flat == window layout!)
#define WS_PART (WS_QWL + Tt*ROW)      // 1200  : part[s][w]
#define WS_CORR (WS_PART + NS*Wn)      // 10    : softmax weights
#define WS_IDX  (WS_CORR + KTOP)       // 10    : window indices (int)

// ---------- Kernel A: Mt = Wk^T Wq (transposed), Bc ----------
__global__ void prep_kernel(const float* __restrict__ Wq, const float* __restrict__ bq,
                            const float* __restrict__ Wk, float* __restrict__ ws) {
    __shared__ float wq[4096], wk[4096];
    for (int i = threadIdx.x; i < 4096; i += 256) { wq[i] = Wq[i]; wk[i] = Wk[i]; }
    __syncthreads();
    float* Mt = ws + WS_MT;
    for (int e = threadIdx.x; e < 4096; e += 256) {
        int cp = e >> 6, c = e & 63;
        float s = 0.f;
        #pragma unroll 8
        for (int o = 0; o < 64; ++o) s += wk[o*64 + c] * wq[o*64 + cp];
        Mt[e] = s;
    }
    if (threadIdx.x < 64) {
        int c = threadIdx.x;
        float s = 0.f;
        #pragma unroll 8
        for (int o = 0; o < 64; ++o) s += wk[o*64 + c] * bq[o];
        ws[WS_BC + c] = 4.0f * s;
    }
}

// ---------- Kernel B: QWl[t][n][c] = sum_c' Mt[c'][c]*Xs[t,n,c'] + Bc[c] ----------
__global__ void qw_kernel(const float* __restrict__ x, float* __restrict__ ws) {
    int blk = blockIdx.x;            // t*N + n
    int t = blk / Nn, n = blk % Nn;
    int c = threadIdx.x;             // 64 threads
    size_t base = ((size_t)t * Nn + n) * 64 + c;
    const size_t bs = (size_t)Tt * Nn * 64;
    float xs = x[base] + x[base + bs] + x[base + 2*bs] + x[base + 3*bs];
    __shared__ float xsl[64];
    xsl[c] = xs;
    __syncthreads();
    const float* Mt = ws + WS_MT;
    float q = ws[WS_BC + c];
    #pragma unroll 8
    for (int cp = 0; cp < 64; ++cp) q += Mt[cp*64 + c] * xsl[cp];
    ws[WS_QWL + (size_t)t * ROW + n*64 + c] = q;
}

// ---------- Kernel C: sims — flat dot per (window, sixth) ----------
// sims_all[w] = flat_dot(QWl, hist + 30w*ROW, Tt*ROW): QWl and a window have
// identical flat layouts. Each block reads a CONTIGUOUS 157KB hist span
// (2 whole rows) + the matching QWl sixth (L2-resident). 38 f4-iters/thread,
// 6 shuffle steps total — long streams, minimal reduction overhead.
__global__ __launch_bounds__(256) void sims_kernel(const float* __restrict__ hist,
                                                   const float* __restrict__ ws_ro,
                                                   float* __restrict__ part) {
    int blk = blockIdx.x;            // 0..1199; adjacent blocks share w (L2 locality)
    int w = blk / NS;
    int s = blk % NS;
    const float4* a = (const float4*)(ws_ro + WS_QWL + (size_t)s * SIXTH);
    const float4* b = (const float4*)(hist + (size_t)(30*w) * ROW + (size_t)s * SIXTH);
    float s0 = 0.f, s1 = 0.f;
    #pragma unroll 4
    for (int i = threadIdx.x; i < SIXTH4; i += 256) {
        float4 av = a[i], bv = b[i];
        s0 += av.x*bv.x + av.y*bv.y;
        s1 += av.z*bv.z + av.w*bv.w;
    }
    float v = s0 + s1;
    #pragma unroll
    for (int off = 32; off > 0; off >>= 1) v += __shfl_down(v, off);
    __shared__ float red[4];
    int wave = threadIdx.x >> 6;
    if ((threadIdx.x & 63) == 0) red[wave] = v;
    __syncthreads();
    if (threadIdx.x == 0)
        part[s*Wn + w] = red[0] + red[1] + red[2] + red[3];
}

// ---------- Kernel D: final — reduce part, top-10 (JAX tie-break), softmax ----------
__global__ void final_kernel(float* __restrict__ ws) {
    __shared__ float simsL[200];
    int tid = threadIdx.x;
    if (tid < 200) {
        const float* part = ws + WS_PART;
        float sum = 0.f;
        #pragma unroll
        for (int s = 0; s < NS; ++s) sum += part[s*Wn + tid];
        simsL[tid] = sum / NUMEL;
    }
    __syncthreads();
    if (tid >= 64) return;
    int lane = tid;                  // one wave does selection
    float v[4]; int ji[4];
    #pragma unroll
    for (int r = 0; r < 4; ++r) {
        int j = lane + 64*r;         // sims index 0..198; value = sims_all[j+1]
        ji[r] = (j < Wn - 1) ? j : (1 << 29);
        v[r]  = (j < Wn - 1) ? simsL[j + 1] : -FLT_MAX;
    }
    float tv[KTOP]; int ti[KTOP];
    for (int k = 0; k < KTOP; ++k) {
        float bv = -FLT_MAX; int bi = 1 << 29;
        #pragma unroll
        for (int r = 0; r < 4; ++r)
            if (v[r] > bv || (v[r] == bv && ji[r] < bi)) { bv = v[r]; bi = ji[r]; }
        #pragma unroll
        for (int off = 32; off > 0; off >>= 1) {
            float ov = __shfl_xor(bv, off);
            int   oi = __shfl_xor(bi, off);
            if (ov > bv || (ov == bv && oi < bi)) { bv = ov; bi = oi; }
        }
        tv[k] = bv; ti[k] = bi;
        #pragma unroll
        for (int r = 0; r < 4; ++r) if (ji[r] == bi) v[r] = -FLT_MAX;
    }
    if (lane == 0) {
        float m = tv[0];
        float sum = 0.f, e[KTOP];
        for (int k = 0; k < KTOP; ++k) { e[k] = __expf(tv[k] - m); sum += e[k]; }
        float inv = 1.0f / sum;
        int* idxout = (int*)(ws + WS_IDX);
        for (int k = 0; k < KTOP; ++k) { ws[WS_CORR + k] = e[k] * inv; idxout[k] = ti[k]; }
    }
}

// ---------- Kernel E: aggregate + Wv/bv + broadcast ----------
__global__ void agg_kernel(const float* __restrict__ hist, const float* __restrict__ Wv,
                           const float* __restrict__ bvv, const float* __restrict__ ws,
                           float* __restrict__ out) {
    int blk = blockIdx.x;            // t*N + n
    int t = blk / Nn, n = blk % Nn;
    int c = threadIdx.x;             // 64 threads; c doubles as output channel o
    const float* corr = ws + WS_CORR;
    const int* topi = (const int*)(ws + WS_IDX);
    float a = 0.f;
    #pragma unroll
    for (int k = 0; k < KTOP; ++k) {
        int w = topi[k];             // reference gathers windows[index] (un-shifted!)
        a += corr[k] * hist[(size_t)(30*w + t) * ROW + n*64 + c];
    }
    __shared__ float aw[64];
    aw[c] = a;
    __syncthreads();
    float acc = bvv[c];
    #pragma unroll 8
    for (int cc = 0; cc < 64; ++cc) acc += Wv[c*64 + cc] * aw[cc];
    #pragma unroll
    for (int b = 0; b < Bb; ++b)
        out[(((size_t)b*Tt + t)*Nn + n)*64 + c] = acc;
}

extern "C" void kernel_launch(void* const* d_in, const int* in_sizes, int n_in,
                              void* d_out, int out_size, void* d_ws, size_t ws_size,
                              hipStream_t stream) {
    const float* x    = (const float*)d_in[0];
    const float* hist = (const float*)d_in[1];
    const float* Wq   = (const float*)d_in[2];
    const float* bq   = (const float*)d_in[3];
    const float* Wk   = (const float*)d_in[4];
    // d_in[5] = bk: unused — uniform shift to all sims; top-k ordering and
    // softmax are shift-invariant, so the output is unaffected.
    const float* Wv   = (const float*)d_in[6];
    const float* bv   = (const float*)d_in[7];
    float* ws  = (float*)d_ws;
    float* out = (float*)d_out;

    prep_kernel<<<1, 256, 0, stream>>>(Wq, bq, Wk, ws);
    qw_kernel<<<NT, 64, 0, stream>>>(x, ws);
    sims_kernel<<<Wn*NS, 256, 0, stream>>>(hist, ws, ws + WS_PART);
    final_kernel<<<1, 256, 0, stream>>>(ws);
    agg_kernel<<<NT, 64, 0, stream>>>(hist, Wv, bv, ws, out);
}

// Round 11
// 70.917 us; speedup vs baseline: 1.1626x; 1.0131x over previous
//
#include <hip/hip_runtime.h>
#include <cfloat>

// Shapes (fixed by reference)
#define Bb 4
#define Tt 12
#define Nn 307
#define Cc 64
#define TH 6000
#define Wn 200        // windows: starts = 0,30,...,5970
#define ROW (Nn*Cc)   // 19648 floats per time-row
#define NT (Tt*Nn)    // 3684
#define KTOP 10
#define NUMEL 943104.0f  // B*64*N*T

// sims decomposition: window x sixth-of-window (a sixth = exactly 2 rows = 157KB)
#define NS 6
#define SIXTH (2*ROW)    // 39296 floats
#define SIXTH4 (SIXTH/4) // 9824 float4s

// workspace layout (float offsets)
#define WS_MT   0                      // 4096  : Mt[c'*64+c]
#define WS_BC   4096                   // 64    : Bc[c]
#define WS_WVT  4160                   // 4096  : WvT[cc*64+o] = Wv[o*64+cc]
#define WS_QWL  (WS_WVT + 4096)        // 235776: QWl[t][n][c]  (flat == window layout!)
#define WS_PART (WS_QWL + Tt*ROW)      // 1200  : part[s][w]
#define WS_CORR (WS_PART + NS*Wn)      // 10    : softmax weights
#define WS_IDX  (WS_CORR + KTOP)       // 10    : window indices (int)

// ---------- Kernel A: Mt = Wk^T Wq (transposed), Bc, WvT ----------
__global__ void prep_kernel(const float* __restrict__ Wq, const float* __restrict__ bq,
                            const float* __restrict__ Wk, const float* __restrict__ Wv,
                            float* __restrict__ ws) {
    __shared__ float wq[4096], wk[4096];
    for (int i = threadIdx.x; i < 4096; i += 256) { wq[i] = Wq[i]; wk[i] = Wk[i]; }
    __syncthreads();
    float* Mt = ws + WS_MT;
    for (int e = threadIdx.x; e < 4096; e += 256) {
        int cp = e >> 6, c = e & 63;
        float s = 0.f;
        #pragma unroll 8
        for (int o = 0; o < 64; ++o) s += wk[o*64 + c] * wq[o*64 + cp];
        Mt[e] = s;
    }
    if (threadIdx.x < 64) {
        int c = threadIdx.x;
        float s = 0.f;
        #pragma unroll 8
        for (int o = 0; o < 64; ++o) s += wk[o*64 + c] * bq[o];
        ws[WS_BC + c] = 4.0f * s;
    }
    // WvT[cc*64 + o] = Wv[o*64 + cc]  (one-time transpose, one block, trivial)
    for (int e = threadIdx.x; e < 4096; e += 256)
        ws[WS_WVT + e] = Wv[(e & 63) * 64 + (e >> 6)];
}

// ---------- Kernel B: QWl[t][n][c] = sum_c' Mt[c'][c]*Xs[t,n,c'] + Bc[c] ----------
__global__ void qw_kernel(const float* __restrict__ x, float* __restrict__ ws) {
    int blk = blockIdx.x;            // t*N + n
    int t = blk / Nn, n = blk % Nn;
    int c = threadIdx.x;             // 64 threads
    size_t base = ((size_t)t * Nn + n) * 64 + c;
    const size_t bs = (size_t)Tt * Nn * 64;
    float xs = x[base] + x[base + bs] + x[base + 2*bs] + x[base + 3*bs];
    __shared__ float xsl[64];
    xsl[c] = xs;
    __syncthreads();
    const float* Mt = ws + WS_MT;
    float q = ws[WS_BC + c];
    #pragma unroll 8
    for (int cp = 0; cp < 64; ++cp) q += Mt[cp*64 + c] * xsl[cp];
    ws[WS_QWL + (size_t)t * ROW + n*64 + c] = q;
}

// ---------- Kernel C: sims — flat dot per (window, sixth) ----------
__global__ __launch_bounds__(256) void sims_kernel(const float* __restrict__ hist,
                                                   const float* __restrict__ ws_ro,
                                                   float* __restrict__ part) {
    int blk = blockIdx.x;            // 0..1199; adjacent blocks share w (L2 locality)
    int w = blk / NS;
    int s = blk % NS;
    const float4* a = (const float4*)(ws_ro + WS_QWL + (size_t)s * SIXTH);
    const float4* b = (const float4*)(hist + (size_t)(30*w) * ROW + (size_t)s * SIXTH);
    float s0 = 0.f, s1 = 0.f;
    #pragma unroll 4
    for (int i = threadIdx.x; i < SIXTH4; i += 256) {
        float4 av = a[i], bv = b[i];
        s0 += av.x*bv.x + av.y*bv.y;
        s1 += av.z*bv.z + av.w*bv.w;
    }
    float v = s0 + s1;
    #pragma unroll
    for (int off = 32; off > 0; off >>= 1) v += __shfl_down(v, off);
    __shared__ float red[4];
    int wave = threadIdx.x >> 6;
    if ((threadIdx.x & 63) == 0) red[wave] = v;
    __syncthreads();
    if (threadIdx.x == 0)
        part[s*Wn + w] = red[0] + red[1] + red[2] + red[3];
}

// ---------- Kernel D: final — reduce part, top-10 (JAX tie-break), softmax ----------
__global__ void final_kernel(float* __restrict__ ws) {
    __shared__ float simsL[200];
    int tid = threadIdx.x;
    if (tid < 200) {
        const float* part = ws + WS_PART;
        float sum = 0.f;
        #pragma unroll
        for (int s = 0; s < NS; ++s) sum += part[s*Wn + tid];
        simsL[tid] = sum / NUMEL;
    }
    __syncthreads();
    if (tid >= 64) return;
    int lane = tid;                  // one wave does selection
    float v[4]; int ji[4];
    #pragma unroll
    for (int r = 0; r < 4; ++r) {
        int j = lane + 64*r;         // sims index 0..198; value = sims_all[j+1]
        ji[r] = (j < Wn - 1) ? j : (1 << 29);
        v[r]  = (j < Wn - 1) ? simsL[j + 1] : -FLT_MAX;
    }
    float tv[KTOP]; int ti[KTOP];
    for (int k = 0; k < KTOP; ++k) {
        float bv = -FLT_MAX; int bi = 1 << 29;
        #pragma unroll
        for (int r = 0; r < 4; ++r)
            if (v[r] > bv || (v[r] == bv && ji[r] < bi)) { bv = v[r]; bi = ji[r]; }
        #pragma unroll
        for (int off = 32; off > 0; off >>= 1) {
            float ov = __shfl_xor(bv, off);
            int   oi = __shfl_xor(bi, off);
            if (ov > bv || (ov == bv && oi < bi)) { bv = ov; bi = oi; }
        }
        tv[k] = bv; ti[k] = bi;
        #pragma unroll
        for (int r = 0; r < 4; ++r) if (ji[r] == bi) v[r] = -FLT_MAX;
    }
    if (lane == 0) {
        float m = tv[0];
        float sum = 0.f, e[KTOP];
        for (int k = 0; k < KTOP; ++k) { e[k] = __expf(tv[k] - m); sum += e[k]; }
        float inv = 1.0f / sum;
        int* idxout = (int*)(ws + WS_IDX);
        for (int k = 0; k < KTOP; ++k) { ws[WS_CORR + k] = e[k] * inv; idxout[k] = ti[k]; }
    }
}

// ---------- Kernel E: aggregate + WvT/bv + broadcast ----------
// WvT[cc*64 + o]: lanes (o) read CONSECUTIVE floats -> 4 cache lines per
// wave-load instead of 64 (the old Wv[o*64+cc] scatter = 4096 L1 line-
// transactions per block).
__global__ void agg_kernel(const float* __restrict__ hist,
                           const float* __restrict__ bvv, const float* __restrict__ ws,
                           float* __restrict__ out) {
    int blk = blockIdx.x;            // t*N + n
    int t = blk / Nn, n = blk % Nn;
    int c = threadIdx.x;             // 64 threads; c doubles as output channel o
    const float* corr = ws + WS_CORR;
    const int* topi = (const int*)(ws + WS_IDX);
    float a = 0.f;
    #pragma unroll
    for (int k = 0; k < KTOP; ++k) {
        int w = topi[k];             // reference gathers windows[index] (un-shifted!)
        a += corr[k] * hist[(size_t)(30*w + t) * ROW + n*64 + c];
    }
    __shared__ float aw[64];
    aw[c] = a;
    __syncthreads();
    const float* WvT = ws + WS_WVT;
    float acc = bvv[c];
    #pragma unroll 8
    for (int cc = 0; cc < 64; ++cc) acc += WvT[cc*64 + c] * aw[cc];
    #pragma unroll
    for (int b = 0; b < Bb; ++b)
        out[(((size_t)b*Tt + t)*Nn + n)*64 + c] = acc;
}

extern "C" void kernel_launch(void* const* d_in, const int* in_sizes, int n_in,
                              void* d_out, int out_size, void* d_ws, size_t ws_size,
                              hipStream_t stream) {
    const float* x    = (const float*)d_in[0];
    const float* hist = (const float*)d_in[1];
    const float* Wq   = (const float*)d_in[2];
    const float* bq   = (const float*)d_in[3];
    const float* Wk   = (const float*)d_in[4];
    // d_in[5] = bk: unused — uniform shift to all sims; top-k ordering and
    // softmax are shift-invariant, so the output is unaffected.
    const float* Wv   = (const float*)d_in[6];
    const float* bv   = (const float*)d_in[7];
    float* ws  = (float*)d_ws;
    float* out = (float*)d_out;

    prep_kernel<<<1, 256, 0, stream>>>(Wq, bq, Wk, Wv, ws);
    qw_kernel<<<NT, 64, 0, stream>>>(x, ws);
    sims_kernel<<<Wn*NS, 256, 0, stream>>>(hist, ws, ws + WS_PART);
    final_kernel<<<1, 256, 0, stream>>>(ws);
    agg_kernel<<<NT, 64, 0, stream>>>(hist, bv, ws, out);
}